// Round 3
// baseline (267.817 us; speedup 1.0000x reference)
//
#include <hip/hip_runtime.h>
#include <hip/hip_bf16.h>
#include <stdint.h>

typedef __hip_bfloat16 bf16;
typedef __attribute__((ext_vector_type(8))) short short8;
typedef __attribute__((ext_vector_type(4))) float f32x4;

#define DEVFN static __device__ __forceinline__

DEVFN unsigned short f2bf(float f) {
    bf16 h = __float2bfloat16(f);
    return __builtin_bit_cast(unsigned short, h);
}

DEVFN void gload_lds16(const void* g, void* l) {
    __builtin_amdgcn_global_load_lds((const __attribute__((address_space(1))) void*)g,
                                     (__attribute__((address_space(3))) void*)l, 16, 0, 0);
}

// ---------------- conversion kernels ----------------

__global__ void cvt_x_kernel(const float* __restrict__ in, bf16* __restrict__ out) {
    int i = blockIdx.x * 256 + threadIdx.x;
    float4 v = ((const float4*)in)[i];
    ushort4 o;
    o.x = f2bf(v.x); o.y = f2bf(v.y); o.z = f2bf(v.z); o.w = f2bf(v.w);
    ((ushort4*)out)[i] = o;
}

// in: f32 [R][C] -> out: bf16 [C][R]
__global__ void transpose_cvt_kernel(const float* __restrict__ in, bf16* __restrict__ out,
                                     int R, int C) {
    __shared__ float tile[32][33];
    int c0 = blockIdx.x * 32, r0 = blockIdx.y * 32;
    int tx = threadIdx.x, ty = threadIdx.y;  // 32 x 8
    #pragma unroll
    for (int i = 0; i < 4; ++i)
        tile[ty + i * 8][tx] = in[(long)(r0 + ty + i * 8) * C + c0 + tx];
    __syncthreads();
    #pragma unroll
    for (int i = 0; i < 4; ++i)
        out[(long)(c0 + ty + i * 8) * R + r0 + tx] = __float2bfloat16(tile[tx][ty + i * 8]);
}

// ---------------- GEMM (m97 structure: 128x128 tile, BK=32) ----------------
// A: [M,1024] bf16 row-major.  BT: [N,1024] bf16 row-major (B transposed).
// EPI 0: QKV epilogue (scatter q/k/v). EPI 1: out-proj epilogue.

template <int EPI>
__global__ __launch_bounds__(256) void gemm_kernel(
    const bf16* __restrict__ A, const bf16* __restrict__ BT, const float* __restrict__ bias,
    float* __restrict__ o_k, float* __restrict__ o_v,
    bf16* __restrict__ qws, bf16* __restrict__ kws, bf16* __restrict__ vws,
    float* __restrict__ outp)
{
    __shared__ bf16 lsA[128 * 32];
    __shared__ bf16 lsB[128 * 32];
    const int t = threadIdx.x;
    const int l = t & 63, w = t >> 6;
    const int lr = l & 15, lg = l >> 4;
    const int bx = blockIdx.x, by = blockIdx.y;
    const int wr = w >> 1, wc = w & 1;

    f32x4 acc[4][4] = {};

    const bf16* gA = A + ((long)by * 128 + (t >> 2)) * 1024 + (t & 3) * 8;
    const bf16* gB = BT + ((long)bx * 128 + (t >> 2)) * 1024 + (t & 3) * 8;
    char* lA = (char*)lsA + w * 1024;  // wave-uniform LDS dest base
    char* lB = (char*)lsB + w * 1024;

    for (int k0 = 0; k0 < 1024; k0 += 32) {
        __syncthreads();
        gload_lds16(gA + k0,         lA);
        gload_lds16(gA + k0 + 65536, lA + 4096);  // rows +64 (64*1024 elems)
        gload_lds16(gB + k0,         lB);
        gload_lds16(gB + k0 + 65536, lB + 4096);
        __syncthreads();

        short8 af[4], bfr[4];
        #pragma unroll
        for (int i = 0; i < 4; ++i)
            af[i] = *(const short8*)((const char*)lsA + (wr * 64 + i * 16 + lr) * 64 + lg * 16);
        #pragma unroll
        for (int j = 0; j < 4; ++j)
            bfr[j] = *(const short8*)((const char*)lsB + (wc * 64 + j * 16 + lr) * 64 + lg * 16);
        #pragma unroll
        for (int i = 0; i < 4; ++i)
            #pragma unroll
            for (int j = 0; j < 4; ++j)
                acc[i][j] = __builtin_amdgcn_mfma_f32_16x16x32_bf16(af[i], bfr[j], acc[i][j], 0, 0, 0);
    }

    const int m0 = by * 128 + wr * 64;
    const int n0 = bx * 128 + wc * 64;
    #pragma unroll
    for (int j = 0; j < 4; ++j) {
        const int cg = n0 + j * 16 + lr;
        const float bv = bias[cg];
        if constexpr (EPI == 0) {
            const int part = cg >> 10, cc = cg & 1023;
            const int h = cc >> 6, dk = cc & 63;
            #pragma unroll
            for (int i = 0; i < 4; ++i) {
                #pragma unroll
                for (int r = 0; r < 4; ++r) {
                    const int rg = m0 + i * 16 + lg * 4 + r;  // C-layout: row=(l>>4)*4+r
                    const int bb = rg >> 11, li = rg & 2047;
                    const float v = acc[i][j][r] + bv;
                    const int idx = ((bb * 16 + h) * 2048 + li) * 64 + dk;
                    if (part == 0) {
                        qws[idx] = __float2bfloat16(v * 0.125f);  // fold 1/sqrt(64), exact
                    } else if (part == 1) {
                        o_k[idx] = v; kws[idx] = __float2bfloat16(v);
                    } else {
                        o_v[idx] = v; vws[idx] = __float2bfloat16(v);
                    }
                }
            }
        } else {
            #pragma unroll
            for (int i = 0; i < 4; ++i)
                #pragma unroll
                for (int r = 0; r < 4; ++r) {
                    const int rg = m0 + i * 16 + lg * 4 + r;
                    outp[(long)rg * 1024 + cg] = acc[i][j][r] + bv;
                }
        }
    }
}

// ---------------- flash attention (causal), swapped-QK^T ----------------
// Q-tile 128/block (4 waves x 32 rows), KV-tile 64. LDS XOR-swizzle (row&7)<<4.

__global__ __launch_bounds__(256) void attn_kernel(
    const bf16* __restrict__ qws, const bf16* __restrict__ kws,
    const bf16* __restrict__ vws, bf16* __restrict__ ctx)
{
    const int bh = blockIdx.y;                     // b*16 + h
    const int qt = 15 - (int)(blockIdx.x & 15);    // heavy tiles dispatched first
    const int qb = qt * 128;
    const int t = threadIdx.x;
    const int l = t & 63, w = t >> 6;
    const int lr = l & 15, lg = l >> 4;

    __shared__ bf16 Kt[64 * 64];      // [kc][dk], swizzled
    __shared__ bf16 Vt[64 * 64];      // transposed: [dv][kc], swizzled
    __shared__ bf16 Pt[4][32 * 64];   // per-wave P [qr][kc], swizzled

    const bf16* Qg = qws + (long)bh * 2048 * 64;
    const bf16* Kg = kws + (long)bh * 2048 * 64;
    const unsigned short* Vg = (const unsigned short*)(vws + (long)bh * 2048 * 64);

    // hoist Q fragments: sub-tile s (16 rows), dk-half kk
    short8 qf[2][2];
    #pragma unroll
    for (int s = 0; s < 2; ++s)
        #pragma unroll
        for (int kk = 0; kk < 2; ++kk)
            qf[s][kk] = *(const short8*)(Qg + (qb + w * 32 + s * 16 + lr) * 64 + kk * 32 + lg * 8);

    f32x4 acc[2][4] = {};
    float mrun[2] = {-1e30f, -1e30f};
    float lsum[2] = {0.f, 0.f};
    const int kvend = qb + 128;

    for (int kv = 0; kv < kvend; kv += 64) {
        __syncthreads();
        // stage K tile (coalesced 16B reads, swizzled LDS writes)
        #pragma unroll
        for (int r = 0; r < 2; ++r) {
            int e = r * 256 + t;
            int row = e >> 3, c16 = (e & 7) * 16;
            short8 kd = *(const short8*)((const char*)Kg + (long)(kv + row) * 128 + c16);
            *(short8*)((char*)Kt + row * 128 + (c16 ^ ((row & 7) << 4))) = kd;
        }
        // stage V transposed: thread -> (dv = lane, 4 consecutive kc)
        #pragma unroll
        for (int it = 0; it < 4; ++it) {
            int dv = l;
            int kc0 = w * 4 + it * 16;
            ushort4 pk;
            pk.x = Vg[(kv + kc0 + 0) * 64 + dv];
            pk.y = Vg[(kv + kc0 + 1) * 64 + dv];
            pk.z = Vg[(kv + kc0 + 2) * 64 + dv];
            pk.w = Vg[(kv + kc0 + 3) * 64 + dv];
            *(ushort4*)((char*)Vt + dv * 128 + ((kc0 * 2) ^ ((dv & 7) << 4))) = pk;
        }
        __syncthreads();

        // S^T = K . Q  -> lane holds S[kc = tt*16+lg*4+r][qr = lr]
        f32x4 st[2][4];
        #pragma unroll
        for (int tt = 0; tt < 4; ++tt) {
            int row = tt * 16 + lr;
            short8 kf0 = *(const short8*)((const char*)Kt + row * 128 + ((lg * 16) ^ ((row & 7) << 4)));
            short8 kf1 = *(const short8*)((const char*)Kt + row * 128 + ((64 + lg * 16) ^ ((row & 7) << 4)));
            #pragma unroll
            for (int s = 0; s < 2; ++s) {
                f32x4 sa = {};
                sa = __builtin_amdgcn_mfma_f32_16x16x32_bf16(kf0, qf[s][0], sa, 0, 0, 0);
                sa = __builtin_amdgcn_mfma_f32_16x16x32_bf16(kf1, qf[s][1], sa, 0, 0, 0);
                st[s][tt] = sa;
            }
        }

        if (kv + 64 > qb) {  // diagonal region: causal mask
            #pragma unroll
            for (int s = 0; s < 2; ++s) {
                int qr = qb + w * 32 + s * 16 + lr;
                #pragma unroll
                for (int tt = 0; tt < 4; ++tt)
                    #pragma unroll
                    for (int r = 0; r < 4; ++r) {
                        int kc = kv + tt * 16 + lg * 4 + r;
                        if (kc > qr) st[s][tt][r] = -1e30f;
                    }
            }
        }

        // online softmax (row stats live at lane qr = lr, replicated over lg)
        #pragma unroll
        for (int s = 0; s < 2; ++s) {
            float mx = -1e30f;
            #pragma unroll
            for (int tt = 0; tt < 4; ++tt)
                #pragma unroll
                for (int r = 0; r < 4; ++r) mx = fmaxf(mx, st[s][tt][r]);
            mx = fmaxf(mx, __shfl_xor(mx, 16));
            mx = fmaxf(mx, __shfl_xor(mx, 32));
            float mnew = fmaxf(mrun[s], mx);
            float corr = __expf(mrun[s] - mnew);
            float ts = 0.f;
            #pragma unroll
            for (int tt = 0; tt < 4; ++tt) {
                float p0 = __expf(st[s][tt][0] - mnew);
                float p1 = __expf(st[s][tt][1] - mnew);
                float p2 = __expf(st[s][tt][2] - mnew);
                float p3 = __expf(st[s][tt][3] - mnew);
                ts += (p0 + p1) + (p2 + p3);
                ushort4 pb;
                pb.x = f2bf(p0); pb.y = f2bf(p1); pb.z = f2bf(p2); pb.w = f2bf(p3);
                int row = s * 16 + lr;
                *(ushort4*)((char*)Pt[w] + row * 128 + ((tt * 32 + lg * 8) ^ ((row & 7) << 4))) = pb;
            }
            ts += __shfl_xor(ts, 16);
            ts += __shfl_xor(ts, 32);
            lsum[s] = lsum[s] * corr + ts;
            mrun[s] = mnew;
            float cb0 = __shfl(corr, lg * 4 + 0);
            float cb1 = __shfl(corr, lg * 4 + 1);
            float cb2 = __shfl(corr, lg * 4 + 2);
            float cb3 = __shfl(corr, lg * 4 + 3);
            #pragma unroll
            for (int j = 0; j < 4; ++j) {
                acc[s][j][0] *= cb0; acc[s][j][1] *= cb1;
                acc[s][j][2] *= cb2; acc[s][j][3] *= cb3;
            }
        }

        // PV: acc[qr][dv] += P . V
        #pragma unroll
        for (int kk = 0; kk < 2; ++kk) {
            short8 pa[2];
            #pragma unroll
            for (int s = 0; s < 2; ++s) {
                int row = s * 16 + lr;
                pa[s] = *(const short8*)((const char*)Pt[w] + row * 128 + ((kk * 64 + lg * 16) ^ ((row & 7) << 4)));
            }
            #pragma unroll
            for (int j = 0; j < 4; ++j) {
                int dv = j * 16 + lr;
                short8 vb = *(const short8*)((const char*)Vt + dv * 128 + ((kk * 64 + lg * 16) ^ ((dv & 7) << 4)));
                #pragma unroll
                for (int s = 0; s < 2; ++s)
                    acc[s][j] = __builtin_amdgcn_mfma_f32_16x16x32_bf16(pa[s], vb, acc[s][j], 0, 0, 0);
            }
        }
    }

    // finalize: ctx[b][l][h*64+dv] = acc / lsum
    const int b = bh >> 4, h = bh & 15;
    #pragma unroll
    for (int s = 0; s < 2; ++s) {
        float i0 = 1.f / __shfl(lsum[s], lg * 4 + 0);
        float i1 = 1.f / __shfl(lsum[s], lg * 4 + 1);
        float i2 = 1.f / __shfl(lsum[s], lg * 4 + 2);
        float i3 = 1.f / __shfl(lsum[s], lg * 4 + 3);
        #pragma unroll
        for (int j = 0; j < 4; ++j) {
            int dv = j * 16 + lr;
            int qr0 = qb + w * 32 + s * 16 + lg * 4;
            long base = ((long)(b * 2048 + qr0)) * 1024 + h * 64 + dv;
            ctx[base]            = __float2bfloat16(acc[s][j][0] * i0);
            ctx[base + 1024]     = __float2bfloat16(acc[s][j][1] * i1);
            ctx[base + 2048]     = __float2bfloat16(acc[s][j][2] * i2);
            ctx[base + 3072]     = __float2bfloat16(acc[s][j][3] * i3);
        }
    }
}

// ---------------- launcher ----------------

extern "C" void kernel_launch(void* const* d_in, const int* in_sizes, int n_in,
                              void* d_out, int out_size, void* d_ws, size_t ws_size,
                              hipStream_t stream) {
    (void)in_sizes; (void)n_in; (void)out_size; (void)ws_size;
    const float* x     = (const float*)d_in[0];
    const float* w_qkv = (const float*)d_in[1];
    const float* b_qkv = (const float*)d_in[2];
    const float* w_o   = (const float*)d_in[3];
    const float* b_o   = (const float*)d_in[4];
    // d_in[5] = mask: causal, implemented analytically

    float* out = (float*)d_out;
    float* o_k = out + 4194304;   // B*L*D
    float* o_v = o_k + 4194304;   // B*H*L*DK

    char* ws = (char*)d_ws;
    bf16* xbf   = (bf16*)(ws);                    //  8 MB: x as bf16 [4096][1024]
    bf16* wqkvT = (bf16*)(ws + (8u  << 20));      //  6 MB: w_qkv^T bf16 [3072][1024]
    bf16* woT   = (bf16*)(ws + (14u << 20));      //  2 MB: w_o^T bf16 [1024][1024]
    bf16* qws   = (bf16*)(ws + (16u << 20));      //  8 MB: q (pre-scaled) [B,H,L,DK]
    bf16* kws   = (bf16*)(ws + (24u << 20));      //  8 MB
    bf16* vws   = (bf16*)(ws + (32u << 20));      //  8 MB
    bf16* ctx   = (bf16*)(ws + (40u << 20));      //  8 MB: attn output [B,L,D]

    cvt_x_kernel<<<4096, 256, 0, stream>>>(x, xbf);
    transpose_cvt_kernel<<<dim3(96, 32), dim3(32, 8), 0, stream>>>(w_qkv, wqkvT, 1024, 3072);
    transpose_cvt_kernel<<<dim3(32, 32), dim3(32, 8), 0, stream>>>(w_o, woT, 1024, 1024);
    gemm_kernel<0><<<dim3(24, 32), 256, 0, stream>>>(xbf, wqkvT, b_qkv, o_k, o_v,
                                                     qws, kws, vws, nullptr);
    attn_kernel<<<dim3(16, 32), 256, 0, stream>>>(qws, kws, vws, ctx);
    gemm_kernel<1><<<dim3(8, 32), 256, 0, stream>>>(ctx, woT, b_o, nullptr, nullptr,
                                                    nullptr, nullptr, nullptr, out);
}

// Round 5
// 215.746 us; speedup vs baseline: 1.2414x; 1.2414x over previous
//
#include <hip/hip_runtime.h>
#include <hip/hip_bf16.h>
#include <stdint.h>

typedef __hip_bfloat16 bf16;
typedef __attribute__((ext_vector_type(8))) short short8;
typedef __attribute__((ext_vector_type(4))) float f32x4;

#define DEVFN static __device__ __forceinline__

DEVFN unsigned short f2bf(float f) {
    bf16 h = __float2bfloat16(f);
    return __builtin_bit_cast(unsigned short, h);
}

DEVFN void gload_lds16(const void* g, void* l) {
    __builtin_amdgcn_global_load_lds((const __attribute__((address_space(1))) void*)g,
                                     (__attribute__((address_space(3))) void*)l, 16, 0, 0);
}

// ---------------- conversion kernels ----------------

__global__ void cvt_x_kernel(const float* __restrict__ in, bf16* __restrict__ out) {
    int i = blockIdx.x * 256 + threadIdx.x;
    float4 v = ((const float4*)in)[i];
    ushort4 o;
    o.x = f2bf(v.x); o.y = f2bf(v.y); o.z = f2bf(v.z); o.w = f2bf(v.w);
    ((ushort4*)out)[i] = o;
}

// in: f32 [R][C] -> out: bf16 [C][R]
__global__ void transpose_cvt_kernel(const float* __restrict__ in, bf16* __restrict__ out,
                                     int R, int C) {
    __shared__ float tile[32][33];
    int c0 = blockIdx.x * 32, r0 = blockIdx.y * 32;
    int tx = threadIdx.x, ty = threadIdx.y;  // 32 x 8
    #pragma unroll
    for (int i = 0; i < 4; ++i)
        tile[ty + i * 8][tx] = in[(long)(r0 + ty + i * 8) * C + c0 + tx];
    __syncthreads();
    #pragma unroll
    for (int i = 0; i < 4; ++i)
        out[(long)(c0 + ty + i * 8) * R + r0 + tx] = __float2bfloat16(tile[tx][ty + i * 8]);
}

// ---------------- GEMM (m97 structure: 128x128 tile, BK=32) ----------------
// A: [M,1024] bf16 row-major.  BT: [N,1024] bf16 row-major (B transposed).
// EPI 0: QKV epilogue (scatter q/k/v). EPI 1: out-proj epilogue.

template <int EPI>
__global__ __launch_bounds__(256) void gemm_kernel(
    const bf16* __restrict__ A, const bf16* __restrict__ BT, const float* __restrict__ bias,
    float* __restrict__ o_k, float* __restrict__ o_v,
    bf16* __restrict__ qws, bf16* __restrict__ kws, bf16* __restrict__ vws,
    float* __restrict__ outp)
{
    __shared__ bf16 lsA[128 * 32];
    __shared__ bf16 lsB[128 * 32];
    const int t = threadIdx.x;
    const int l = t & 63, w = t >> 6;
    const int lr = l & 15, lg = l >> 4;
    const int bx = blockIdx.x, by = blockIdx.y;
    const int wr = w >> 1, wc = w & 1;

    f32x4 acc[4][4] = {};

    const bf16* gA = A + ((long)by * 128 + (t >> 2)) * 1024 + (t & 3) * 8;
    const bf16* gB = BT + ((long)bx * 128 + (t >> 2)) * 1024 + (t & 3) * 8;
    char* lA = (char*)lsA + w * 1024;  // wave-uniform LDS dest base
    char* lB = (char*)lsB + w * 1024;

    for (int k0 = 0; k0 < 1024; k0 += 32) {
        __syncthreads();
        gload_lds16(gA + k0,         lA);
        gload_lds16(gA + k0 + 65536, lA + 4096);  // rows +64 (64*1024 elems)
        gload_lds16(gB + k0,         lB);
        gload_lds16(gB + k0 + 65536, lB + 4096);
        __syncthreads();

        short8 af[4], bfr[4];
        #pragma unroll
        for (int i = 0; i < 4; ++i)
            af[i] = *(const short8*)((const char*)lsA + (wr * 64 + i * 16 + lr) * 64 + lg * 16);
        #pragma unroll
        for (int j = 0; j < 4; ++j)
            bfr[j] = *(const short8*)((const char*)lsB + (wc * 64 + j * 16 + lr) * 64 + lg * 16);
        #pragma unroll
        for (int i = 0; i < 4; ++i)
            #pragma unroll
            for (int j = 0; j < 4; ++j)
                acc[i][j] = __builtin_amdgcn_mfma_f32_16x16x32_bf16(af[i], bfr[j], acc[i][j], 0, 0, 0);
    }

    const int m0 = by * 128 + wr * 64;
    const int n0 = bx * 128 + wc * 64;
    #pragma unroll
    for (int j = 0; j < 4; ++j) {
        const int cg = n0 + j * 16 + lr;
        const float bv = bias[cg];
        if constexpr (EPI == 0) {
            const int part = cg >> 10, cc = cg & 1023;
            const int h = cc >> 6, dk = cc & 63;
            #pragma unroll
            for (int i = 0; i < 4; ++i) {
                #pragma unroll
                for (int r = 0; r < 4; ++r) {
                    const int rg = m0 + i * 16 + lg * 4 + r;  // C-layout: row=(l>>4)*4+r
                    const int bb = rg >> 11, li = rg & 2047;
                    const float v = acc[i][j][r] + bv;
                    const int idx = ((bb * 16 + h) * 2048 + li) * 64 + dk;
                    if (part == 0) {
                        qws[idx] = __float2bfloat16(v * 0.125f);  // fold 1/sqrt(64), exact
                    } else if (part == 1) {
                        o_k[idx] = v; kws[idx] = __float2bfloat16(v);
                    } else {
                        o_v[idx] = v; vws[idx] = __float2bfloat16(v);
                    }
                }
            }
        } else {
            #pragma unroll
            for (int i = 0; i < 4; ++i)
                #pragma unroll
                for (int r = 0; r < 4; ++r) {
                    const int rg = m0 + i * 16 + lg * 4 + r;
                    outp[(long)rg * 1024 + cg] = acc[i][j][r] + bv;
                }
        }
    }
}

// ---------------- flash attention (causal), swapped-QK^T ----------------
// QBLK=64 (4 waves x 16 q-rows), KVBLK=64, heavy-tiles-first on grid.y.
// 32 tiles x 32 bh = 1024 blocks -> 4 blocks/CU (was 512 -> 2/CU).

__global__ __launch_bounds__(256) void attn_kernel(
    const bf16* __restrict__ qws, const bf16* __restrict__ kws,
    const bf16* __restrict__ vws, bf16* __restrict__ ctx)
{
    const int bh = blockIdx.x;                     // b*16 + h
    const int qt = 31 - (int)blockIdx.y;           // heavy tiles dispatched first
    const int qb = qt * 64;
    const int t = threadIdx.x;
    const int l = t & 63, w = t >> 6;
    const int lr = l & 15, lg = l >> 4;

    __shared__ bf16 Kt[64 * 64];      // [kc][dk], swizzled
    __shared__ bf16 Vt[64 * 64];      // transposed: [dv][kc], swizzled
    __shared__ bf16 Pt[4][16 * 64];   // per-wave P [qr][kc], swizzled

    const bf16* Qg = qws + (long)bh * 2048 * 64;
    const bf16* Kg = kws + (long)bh * 2048 * 64;
    const unsigned short* Vg = (const unsigned short*)(vws + (long)bh * 2048 * 64);

    // hoist Q fragments: wave owns rows [qb + w*16, +16); kk = dk-half
    short8 qf[2];
    #pragma unroll
    for (int kk = 0; kk < 2; ++kk)
        qf[kk] = *(const short8*)(Qg + (qb + w * 16 + lr) * 64 + kk * 32 + lg * 8);

    f32x4 acc[4] = {};
    float mrun = -1e30f;
    float lsum = 0.f;
    const int kvend = qb + 64;

    for (int kv = 0; kv < kvend; kv += 64) {
        __syncthreads();
        // stage K tile (coalesced 16B reads, swizzled LDS writes)
        #pragma unroll
        for (int r = 0; r < 2; ++r) {
            int e = r * 256 + t;
            int row = e >> 3, c16 = (e & 7) * 16;
            short8 kd = *(const short8*)((const char*)Kg + (long)(kv + row) * 128 + c16);
            *(short8*)((char*)Kt + row * 128 + (c16 ^ ((row & 7) << 4))) = kd;
        }
        // stage V transposed: thread -> (dv = lane, 4 consecutive kc)
        #pragma unroll
        for (int it = 0; it < 4; ++it) {
            int dv = l;
            int kc0 = w * 4 + it * 16;
            ushort4 pk;
            pk.x = Vg[(kv + kc0 + 0) * 64 + dv];
            pk.y = Vg[(kv + kc0 + 1) * 64 + dv];
            pk.z = Vg[(kv + kc0 + 2) * 64 + dv];
            pk.w = Vg[(kv + kc0 + 3) * 64 + dv];
            *(ushort4*)((char*)Vt + dv * 128 + ((kc0 * 2) ^ ((dv & 7) << 4))) = pk;
        }
        __syncthreads();

        // S^T = K . Q  -> lane holds S[kc = tt*16+lg*4+r][qr = lr]
        f32x4 st[4];
        #pragma unroll
        for (int tt = 0; tt < 4; ++tt) {
            int row = tt * 16 + lr;
            short8 kf0 = *(const short8*)((const char*)Kt + row * 128 + ((lg * 16) ^ ((row & 7) << 4)));
            short8 kf1 = *(const short8*)((const char*)Kt + row * 128 + ((64 + lg * 16) ^ ((row & 7) << 4)));
            f32x4 sa = {};
            sa = __builtin_amdgcn_mfma_f32_16x16x32_bf16(kf0, qf[0], sa, 0, 0, 0);
            sa = __builtin_amdgcn_mfma_f32_16x16x32_bf16(kf1, qf[1], sa, 0, 0, 0);
            st[tt] = sa;
        }

        if (kv + 64 > qb) {  // diagonal tile: causal mask
            int qr = qb + w * 16 + lr;
            #pragma unroll
            for (int tt = 0; tt < 4; ++tt)
                #pragma unroll
                for (int r = 0; r < 4; ++r) {
                    int kc = kv + tt * 16 + lg * 4 + r;
                    if (kc > qr) st[tt][r] = -1e30f;
                }
        }

        // online softmax (row stats live at lane qr = lr, replicated over lg)
        {
            float mx = -1e30f;
            #pragma unroll
            for (int tt = 0; tt < 4; ++tt)
                #pragma unroll
                for (int r = 0; r < 4; ++r) mx = fmaxf(mx, st[tt][r]);
            mx = fmaxf(mx, __shfl_xor(mx, 16));
            mx = fmaxf(mx, __shfl_xor(mx, 32));
            float mnew = fmaxf(mrun, mx);
            float corr = __expf(mrun - mnew);
            float ts = 0.f;
            #pragma unroll
            for (int tt = 0; tt < 4; ++tt) {
                float p0 = __expf(st[tt][0] - mnew);
                float p1 = __expf(st[tt][1] - mnew);
                float p2 = __expf(st[tt][2] - mnew);
                float p3 = __expf(st[tt][3] - mnew);
                ts += (p0 + p1) + (p2 + p3);
                ushort4 pb;
                pb.x = f2bf(p0); pb.y = f2bf(p1); pb.z = f2bf(p2); pb.w = f2bf(p3);
                int row = lr;
                *(ushort4*)((char*)Pt[w] + row * 128 + ((tt * 32 + lg * 8) ^ ((row & 7) << 4))) = pb;
            }
            ts += __shfl_xor(ts, 16);
            ts += __shfl_xor(ts, 32);
            lsum = lsum * corr + ts;
            mrun = mnew;
            float cb0 = __shfl(corr, lg * 4 + 0);
            float cb1 = __shfl(corr, lg * 4 + 1);
            float cb2 = __shfl(corr, lg * 4 + 2);
            float cb3 = __shfl(corr, lg * 4 + 3);
            #pragma unroll
            for (int j = 0; j < 4; ++j) {
                acc[j][0] *= cb0; acc[j][1] *= cb1;
                acc[j][2] *= cb2; acc[j][3] *= cb3;
            }
        }

        // PV: acc[qr][dv] += P . V
        #pragma unroll
        for (int kk = 0; kk < 2; ++kk) {
            int row = lr;
            short8 pa = *(const short8*)((const char*)Pt[w] + row * 128 + ((kk * 64 + lg * 16) ^ ((row & 7) << 4)));
            #pragma unroll
            for (int j = 0; j < 4; ++j) {
                int dv = j * 16 + lr;
                short8 vb = *(const short8*)((const char*)Vt + dv * 128 + ((kk * 64 + lg * 16) ^ ((dv & 7) << 4)));
                acc[j] = __builtin_amdgcn_mfma_f32_16x16x32_bf16(pa, vb, acc[j], 0, 0, 0);
            }
        }
    }

    // finalize: ctx[b][l][h*64+dv] = acc / lsum
    const int b = bh >> 4, h = bh & 15;
    {
        float i0 = 1.f / __shfl(lsum, lg * 4 + 0);
        float i1 = 1.f / __shfl(lsum, lg * 4 + 1);
        float i2 = 1.f / __shfl(lsum, lg * 4 + 2);
        float i3 = 1.f / __shfl(lsum, lg * 4 + 3);
        #pragma unroll
        for (int j = 0; j < 4; ++j) {
            int dv = j * 16 + lr;
            int qr0 = qb + w * 16 + lg * 4;
            long base = ((long)(b * 2048 + qr0)) * 1024 + h * 64 + dv;
            ctx[base]            = __float2bfloat16(acc[j][0] * i0);
            ctx[base + 1024]     = __float2bfloat16(acc[j][1] * i1);
            ctx[base + 2048]     = __float2bfloat16(acc[j][2] * i2);
            ctx[base + 3072]     = __float2bfloat16(acc[j][3] * i3);
        }
    }
}

// ---------------- launcher ----------------

extern "C" void kernel_launch(void* const* d_in, const int* in_sizes, int n_in,
                              void* d_out, int out_size, void* d_ws, size_t ws_size,
                              hipStream_t stream) {
    (void)in_sizes; (void)n_in; (void)out_size; (void)ws_size;
    const float* x     = (const float*)d_in[0];
    const float* w_qkv = (const float*)d_in[1];
    const float* b_qkv = (const float*)d_in[2];
    const float* w_o   = (const float*)d_in[3];
    const float* b_o   = (const float*)d_in[4];
    // d_in[5] = mask: causal, implemented analytically

    float* out = (float*)d_out;
    float* o_k = out + 4194304;   // B*L*D
    float* o_v = o_k + 4194304;   // B*H*L*DK

    char* ws = (char*)d_ws;
    bf16* xbf   = (bf16*)(ws);                    //  8 MB: x as bf16 [4096][1024]
    bf16* wqkvT = (bf16*)(ws + (8u  << 20));      //  6 MB: w_qkv^T bf16 [3072][1024]
    bf16* woT   = (bf16*)(ws + (14u << 20));      //  2 MB: w_o^T bf16 [1024][1024]
    bf16* qws   = (bf16*)(ws + (16u << 20));      //  8 MB: q (pre-scaled) [B,H,L,DK]
    bf16* kws   = (bf16*)(ws + (24u << 20));      //  8 MB
    bf16* vws   = (bf16*)(ws + (32u << 20));      //  8 MB
    bf16* ctx   = (bf16*)(ws + (40u << 20));      //  8 MB: attn output [B,L,D]

    cvt_x_kernel<<<4096, 256, 0, stream>>>(x, xbf);
    transpose_cvt_kernel<<<dim3(96, 32), dim3(32, 8), 0, stream>>>(w_qkv, wqkvT, 1024, 3072);
    transpose_cvt_kernel<<<dim3(32, 32), dim3(32, 8), 0, stream>>>(w_o, woT, 1024, 1024);
    gemm_kernel<0><<<dim3(24, 32), 256, 0, stream>>>(xbf, wqkvT, b_qkv, o_k, o_v,
                                                     qws, kws, vws, nullptr);
    attn_kernel<<<dim3(32, 32), 256, 0, stream>>>(qws, kws, vws, ctx);
    gemm_kernel<1><<<dim3(8, 32), 256, 0, stream>>>(ctx, woT, b_o, nullptr, nullptr,
                                                    nullptr, nullptr, nullptr, out);
}